// Round 12
// baseline (1412.300 us; speedup 1.0000x reference)
//
#include <hip/hip_runtime.h>
#include <hip/hip_bf16.h>
#include <hip/hip_cooperative_groups.h>
#include <cstdint>

namespace cg = cooperative_groups;

#define NV 20000
#define NE 40000
#define NODE_IN 74
#define EDGE_IN 12
#define D 64
#define EHID 128
#define NSTEPS 6

typedef __bf16 bf16x8 __attribute__((ext_vector_type(8)));
typedef float f32x4 __attribute__((ext_vector_type(4)));

// ---------------- node projection: h = relu(nf @ Wp^T + bp); also zero neigh ----------------
__global__ __launch_bounds__(256) void k_proj(const float* __restrict__ nf,
                                              const float* __restrict__ W,
                                              const float* __restrict__ b,
                                              float* __restrict__ h,
                                              float* __restrict__ neigh) {
  __shared__ float sn[4][NODE_IN];
  int tid = threadIdx.x;
  int nb = blockIdx.x * 4;
  for (int idx = tid; idx < 4 * NODE_IN; idx += 256) {
    int r = idx / NODE_IN, c = idx % NODE_IN;
    sn[r][c] = nf[(size_t)(nb + r) * NODE_IN + c];
  }
  __syncthreads();
  int nl = tid >> 6, o = tid & 63;
  float acc = b[o];
#pragma unroll
  for (int i = 0; i < NODE_IN; ++i) acc = fmaf(sn[nl][i], W[o * NODE_IN + i], acc);
  h[(size_t)(nb + nl) * D + o] = fmaxf(acc, 0.f);
  neigh[(size_t)(nb + nl) * D + o] = 0.f;
}

// ------------- edge net layer 1: t = relu(ef @ W1^T + b1), bf16 -------------
__global__ __launch_bounds__(256) void k_edge1(const float* __restrict__ ef,
                                               const float* __restrict__ W1,
                                               const float* __restrict__ b1,
                                               __hip_bfloat16* __restrict__ t_bf) {
  __shared__ float se[2][EDGE_IN];
  int tid = threadIdx.x;
  int eb = blockIdx.x * 2;
  if (tid < 2 * EDGE_IN)
    se[tid / EDGE_IN][tid % EDGE_IN] =
        ef[(size_t)(eb + tid / EDGE_IN) * EDGE_IN + tid % EDGE_IN];
  __syncthreads();
  int el = tid >> 7, k = tid & 127;
  float acc = b1[k];
#pragma unroll
  for (int j = 0; j < EDGE_IN; ++j) acc = fmaf(se[el][j], W1[k * EDGE_IN + j], acc);
  t_bf[(size_t)(eb + el) * EHID + k] = __float2bfloat16(fmaxf(acc, 0.f));
}

// ---------------- W2 fp32 -> bf16 ----------------
__global__ __launch_bounds__(256) void k_cvt_w2(const float* __restrict__ W2,
                                                __hip_bfloat16* __restrict__ w2b) {
  int idx = blockIdx.x * 256 + threadIdx.x;
  if (idx < D * D * EHID) w2b[idx] = __float2bfloat16(W2[idx]);
}

// ---------------- b2 transpose: b2t[o][i] = b2[i*64+o], bf16 ----------------
__global__ __launch_bounds__(256) void k_b2t(const float* __restrict__ b2,
                                             __hip_bfloat16* __restrict__ b2t) {
  int idx = blockIdx.x * 256 + threadIdx.x;  // 4096
  int o = idx >> 6, i = idx & 63;
  b2t[o * 64 + i] = __float2bfloat16(b2[i * 64 + o]);
}

// ------- build GRU B matrix (256 x 128), hi/lo bf16 split -------
__global__ __launch_bounds__(256) void k_build_b(const float* __restrict__ Wih,
                                                 const float* __restrict__ Whh,
                                                 __hip_bfloat16* __restrict__ Bhi,
                                                 __hip_bfloat16* __restrict__ Blo) {
  int idx = blockIdx.x * 256 + threadIdx.x;  // 32768 total
  int n = idx >> 7, k = idx & 127;
  int o = n & 63, cls = n >> 6;
  float v;
  if (cls == 0)      v = (k < 64) ? Wih[o * 64 + k]         : Whh[o * 64 + (k - 64)];
  else if (cls == 1) v = (k < 64) ? Wih[(64 + o) * 64 + k]  : Whh[(64 + o) * 64 + (k - 64)];
  else if (cls == 2) v = (k < 64) ? Wih[(128 + o) * 64 + k] : 0.f;
  else               v = (k < 64) ? 0.f                     : Whh[(128 + o) * 64 + (k - 64)];
  __hip_bfloat16 hi = __float2bfloat16(v);
  Bhi[idx] = hi;
  Blo[idx] = __float2bfloat16(v - __bfloat162float(hi));
}

// ======= cooperative fused 6-step loop: msg phase (R11 body) + gru phase (R8 body) =======
// Grid: EXACTLY 256 blocks (1/CU; LDS 147 KB forces 1 block/CU -> co-resident) x 512 thr.
// W2 slice loaded into LDS ONCE for all 6 steps. Per step: barrier-free msg phase
// (atomics into neigh), grid.sync, gru phase (625 32-node groups strided by 256,
// Hs reused as Ahi/Alo), grid.sync.
__global__ __launch_bounds__(512, 2) void k_loop(float* __restrict__ h,
                                                 const __hip_bfloat16* __restrict__ t_bf,
                                                 const __hip_bfloat16* __restrict__ w2,
                                                 const __hip_bfloat16* __restrict__ b2t,
                                                 const __hip_bfloat16* __restrict__ Bhi,
                                                 const __hip_bfloat16* __restrict__ Blo,
                                                 const float* __restrict__ cb,
                                                 const float* __restrict__ bih,
                                                 const float* __restrict__ bhh,
                                                 const int* __restrict__ src,
                                                 const int* __restrict__ dst,
                                                 float* __restrict__ neigh) {
  cg::grid_group gg = cg::this_grid();
  __shared__ __hip_bfloat16 W2s[512 * 128];   // 128 KB, persistent all 6 steps
  __shared__ __hip_bfloat16 Hs[8 * 1024];     // 16 KB: msg per-wave h-tiles / gru Ahi+Alo
  int tid = threadIdx.x;
  int bx = blockIdx.x;
  int cgc = bx >> 6, ih = (bx >> 5) & 1, st = bx & 31;
  int lane = tid & 63, lr = lane & 15, lq = lane >> 4;
  int wave = tid >> 6;
  const int ocol = cgc * 16 + lr;

  // ---- load W2 slice into LDS (ONCE for the whole kernel) ----
#pragma unroll
  for (int it = 0; it < 16; ++it) {
    int chunk = it * 512 + tid;
    int row = chunk >> 4, c = chunk & 15;
    int ig = row >> 4, ol = row & 15;
    const __hip_bfloat16* gp =
        w2 + ((size_t)((ih * 32 + ig) * 64 + cgc * 16 + ol)) * EHID + c * 8;
    *(bf16x8*)(W2s + row * 128 + ((c ^ ol) * 8)) = *(const bf16x8*)gp;
  }
  // phase-masked b2 B-frags
  bf16x8 b2f0, b2f1;
#pragma unroll
  for (int j = 0; j < 8; ++j) {
    int k = lq * 8 + j;
    __bf16 v = *(const __bf16*)(b2t + (size_t)ocol * 64 + ih * 32 + k);
    __bf16 z = (__bf16)0.0f;
    b2f0[j] = (k < 16) ? v : z;
    b2f1[j] = (k >= 16) ? v : z;
  }
  __syncthreads();  // W2s ready (block-local is enough)

  __hip_bfloat16* Hsw = Hs + wave * 1024;
  int e0s = st * 1280;
  int nt = (st < 31) ? 20 : 5;  // 40000 = 31*1280 + 320

  int sw0 = (((0 * 4 + lq) ^ lr) * 8);
  int sw1 = (((1 * 4 + lq) ^ lr) * 8);
  int sw2 = (((2 * 4 + lq) ^ lr) * 8);
  int sw3 = (((3 * 4 + lq) ^ lr) * 8);

  // gru-phase roles
  int colg = wave & 3, mth = wave >> 2;
  int og = colg * 16 + lr;
  float b_r = bih[og] + bhh[og];
  float b_z = bih[64 + og] + bhh[64 + og];
  float b_in = bih[128 + og];
  float b_hn = bhh[128 + og];

#pragma unroll 1
  for (int step = 0; step < NSTEPS; ++step) {
    // ================= msg phase (R11 body, barrier-free) =================
#pragma unroll 1
    for (int r3 = 0; r3 < 3; ++r3) {
      int t = r3 * 8 + wave;
      if (t < nt) {
        int e0t = e0s + t * 64;
        bf16x8 tf[4][4];
#pragma unroll
        for (int mt = 0; mt < 4; ++mt)
#pragma unroll
          for (int ks = 0; ks < 4; ++ks)
            tf[mt][ks] = *(const bf16x8*)(t_bf + (size_t)(e0t + mt * 16 + lr) * EHID +
                                          ks * 32 + lq * 8);
        int s_e = src[e0t + lane];
        const float* hrow = h + (size_t)s_e * D + ih * 32;
        f32x4 C[4];
#pragma unroll
        for (int mt = 0; mt < 4; ++mt) C[mt] = f32x4{0.f, 0.f, 0.f, 0.f};

#pragma unroll
        for (int ph = 0; ph < 2; ++ph) {
#pragma unroll
          for (int q = 0; q < 4; ++q) {
            float4 hv = *(const float4*)(hrow + ph * 16 + q * 4);
            Hsw[(q * 4 + 0) * 64 + lane] = __float2bfloat16(hv.x);
            Hsw[(q * 4 + 1) * 64 + lane] = __float2bfloat16(hv.y);
            Hsw[(q * 4 + 2) * 64 + lane] = __float2bfloat16(hv.z);
            Hsw[(q * 4 + 3) * 64 + lane] = __float2bfloat16(hv.w);
          }
#pragma unroll
          for (int mt = 0; mt < 4; ++mt) {
            bf16x8 af;
#pragma unroll
            for (int j = 0; j < 8; ++j)
              af[j] = *(const __bf16*)(Hsw + ((lq * 8 + j) & 15) * 64 + mt * 16 + lr);
            C[mt] = __builtin_amdgcn_mfma_f32_16x16x32_bf16(af, ph ? b2f1 : b2f0, C[mt], 0, 0, 0);
          }
#pragma unroll 2
          for (int igl = 0; igl < 16; ++igl) {
            int ig = ph * 16 + igl;
            const __hip_bfloat16* Wr = W2s + (ig * 16 + lr) * 128;
            bf16x8 f0 = *(const bf16x8*)(Wr + sw0);
            bf16x8 f1 = *(const bf16x8*)(Wr + sw1);
            bf16x8 f2 = *(const bf16x8*)(Wr + sw2);
            bf16x8 f3 = *(const bf16x8*)(Wr + sw3);
#pragma unroll
            for (int mt = 0; mt < 4; ++mt) {
              f32x4 P = {0.f, 0.f, 0.f, 0.f};
              P = __builtin_amdgcn_mfma_f32_16x16x32_bf16(tf[mt][0], f0, P, 0, 0, 0);
              P = __builtin_amdgcn_mfma_f32_16x16x32_bf16(tf[mt][1], f1, P, 0, 0, 0);
              P = __builtin_amdgcn_mfma_f32_16x16x32_bf16(tf[mt][2], f2, P, 0, 0, 0);
              P = __builtin_amdgcn_mfma_f32_16x16x32_bf16(tf[mt][3], f3, P, 0, 0, 0);
              uint2 hA = *(const uint2*)(Hsw + igl * 64 + mt * 16 + lq * 4);
              C[mt][0] = fmaf(__uint_as_float(hA.x << 16), P[0], C[mt][0]);
              C[mt][1] = fmaf(__uint_as_float(hA.x & 0xffff0000u), P[1], C[mt][1]);
              C[mt][2] = fmaf(__uint_as_float(hA.y << 16), P[2], C[mt][2]);
              C[mt][3] = fmaf(__uint_as_float(hA.y & 0xffff0000u), P[3], C[mt][3]);
            }
          }
        }
#pragma unroll
        for (int mt = 0; mt < 4; ++mt) {
#pragma unroll
          for (int r = 0; r < 4; ++r) {
            int ea = e0t + mt * 16 + lq * 4 + r;
            atomicAdd(neigh + (size_t)dst[ea] * D + ocol, C[mt][r]);
          }
        }
      }
    }
    __threadfence();
    gg.sync();  // all atomics into neigh visible

    // ================= gru phase (R8 body, 512-thread indexing) =================
    __hip_bfloat16* Ahi = Hs;
    __hip_bfloat16* Alo = Hs + 4096;
#pragma unroll 1
    for (int g = bx; g < 625; g += 256) {
      int n0 = g * 32;
      __syncthreads();  // previous group's readers done before overwrite
      for (int idx = tid; idx < 32 * 64; idx += 512) {
        int node = idx >> 6, f = idx & 63;
        int gn = n0 + node;
        float xv = fmaxf(neigh[(size_t)gn * D + f] + cb[f], 0.f);
        neigh[(size_t)gn * D + f] = 0.f;
        float hv = h[(size_t)gn * D + f];
        __hip_bfloat16 xh = __float2bfloat16(xv);
        __hip_bfloat16 hh = __float2bfloat16(hv);
        Ahi[node * 128 + f] = xh;
        Ahi[node * 128 + 64 + f] = hh;
        Alo[node * 128 + f] = __float2bfloat16(xv - __bfloat162float(xh));
        Alo[node * 128 + 64 + f] = __float2bfloat16(hv - __bfloat162float(hh));
      }
      __syncthreads();
      f32x4 acc[4] = {};  // [gate-class], single m-tile = mth
#pragma unroll
      for (int ks = 0; ks < 4; ++ks) {
        int koff = ks * 32 + lq * 8;
        bf16x8 ah, al, bh[4], bl[4];
        ah = *(const bf16x8*)(Ahi + (mth * 16 + lr) * 128 + koff);
        al = *(const bf16x8*)(Alo + (mth * 16 + lr) * 128 + koff);
#pragma unroll
        for (int cls = 0; cls < 4; ++cls) {
          int n = cls * 64 + colg * 16 + lr;
          bh[cls] = *(const bf16x8*)(Bhi + (size_t)n * 128 + koff);
          bl[cls] = *(const bf16x8*)(Blo + (size_t)n * 128 + koff);
        }
#pragma unroll
        for (int cls = 0; cls < 4; ++cls) {
          acc[cls] = __builtin_amdgcn_mfma_f32_16x16x32_bf16(ah, bh[cls], acc[cls], 0, 0, 0);
          acc[cls] = __builtin_amdgcn_mfma_f32_16x16x32_bf16(al, bh[cls], acc[cls], 0, 0, 0);
          acc[cls] = __builtin_amdgcn_mfma_f32_16x16x32_bf16(ah, bl[cls], acc[cls], 0, 0, 0);
        }
      }
#pragma unroll
      for (int r = 0; r < 4; ++r) {
        int gn = n0 + mth * 16 + lq * 4 + r;
        float rs = acc[0][r] + b_r;
        float zs = acc[1][r] + b_z;
        float inn = acc[2][r] + b_in;
        float hnn = acc[3][r] + b_hn;
        float rg = 1.f / (1.f + __expf(-rs));
        float zg = 1.f / (1.f + __expf(-zs));
        float a = inn + rg * hnn;
        a = fminf(fmaxf(a, -15.f), 15.f);
        float e2 = __expf(2.f * a);
        float nn = (e2 - 1.f) / (e2 + 1.f);
        float hold = h[(size_t)gn * D + og];
        h[(size_t)gn * D + og] = (1.f - zg) * nn + zg * hold;
      }
    }
    __threadfence();
    gg.sync();  // h updates visible before next step's gather
  }
}

// ---------------- predictor: score_e = [h_src | h_dst] . pW + pb ----------------
__global__ __launch_bounds__(256) void k_pred(const float* __restrict__ h,
                                              const int* __restrict__ src,
                                              const int* __restrict__ dst,
                                              const float* __restrict__ pW,
                                              const float* __restrict__ pb,
                                              float* __restrict__ out) {
  int wave = threadIdx.x >> 6, lane = threadIdx.x & 63;
  int e = blockIdx.x * 4 + wave;
  int s = src[e], d2 = dst[e];
  float v = h[(size_t)s * D + lane] * pW[lane] + h[(size_t)d2 * D + lane] * pW[64 + lane];
#pragma unroll
  for (int off = 32; off >= 1; off >>= 1) v += __shfl_xor(v, off, 64);
  if (lane == 0) out[e] = v + pb[0];
}

extern "C" void kernel_launch(void* const* d_in, const int* in_sizes, int n_in,
                              void* d_out, int out_size, void* d_ws, size_t ws_size,
                              hipStream_t stream) {
  const float* node_feats = (const float*)d_in[0];
  const float* edge_feats = (const float*)d_in[1];
  const int* src = (const int*)d_in[2];
  const int* dst = (const int*)d_in[3];
  const float* proj_W = (const float*)d_in[4];
  const float* proj_b = (const float*)d_in[5];
  const float* en_W1 = (const float*)d_in[6];
  const float* en_b1 = (const float*)d_in[7];
  const float* en_W2 = (const float*)d_in[8];
  const float* en_b2 = (const float*)d_in[9];
  const float* conv_b = (const float*)d_in[10];
  const float* gru_Wih = (const float*)d_in[11];
  const float* gru_Whh = (const float*)d_in[12];
  const float* gru_bih = (const float*)d_in[13];
  const float* gru_bhh = (const float*)d_in[14];
  const float* pred_W = (const float*)d_in[15];
  const float* pred_b = (const float*)d_in[16];

  char* ws = (char*)d_ws;
  size_t off = 0;
  auto walloc = [&](size_t bytes) -> void* {
    void* p = ws + off;
    off = (off + bytes + 255) & ~(size_t)255;
    return p;
  };
  float* h = (float*)walloc((size_t)NV * D * 4);
  float* neigh = (float*)walloc((size_t)NV * D * 4);
  __hip_bfloat16* t_bf = (__hip_bfloat16*)walloc((size_t)NE * EHID * 2);
  __hip_bfloat16* w2_bf = (__hip_bfloat16*)walloc((size_t)D * D * EHID * 2);
  __hip_bfloat16* b2t = (__hip_bfloat16*)walloc((size_t)D * D * 2);
  __hip_bfloat16* Bhi = (__hip_bfloat16*)walloc((size_t)256 * 128 * 2);
  __hip_bfloat16* Blo = (__hip_bfloat16*)walloc((size_t)256 * 128 * 2);

  k_proj<<<NV / 4, 256, 0, stream>>>(node_feats, proj_W, proj_b, h, neigh);
  k_edge1<<<NE / 2, 256, 0, stream>>>(edge_feats, en_W1, en_b1, t_bf);
  k_cvt_w2<<<(D * D * EHID + 255) / 256, 256, 0, stream>>>(en_W2, w2_bf);
  k_b2t<<<(D * D + 255) / 256, 256, 0, stream>>>(en_b2, b2t);
  k_build_b<<<128, 256, 0, stream>>>(gru_Wih, gru_Whh, Bhi, Blo);

  void* kargs[] = {(void*)&h,    (void*)&t_bf, (void*)&w2_bf, (void*)&b2t,
                   (void*)&Bhi,  (void*)&Blo,  (void*)&conv_b, (void*)&gru_bih,
                   (void*)&gru_bhh, (void*)&src, (void*)&dst,  (void*)&neigh};
  hipLaunchCooperativeKernel((const void*)k_loop, dim3(256), dim3(512), kargs, 0, stream);

  k_pred<<<NE / 4, 256, 0, stream>>>(h, src, dst, pred_W, pred_b, (float*)d_out);
}

// Round 13
// 514.279 us; speedup vs baseline: 2.7462x; 2.7462x over previous
//
#include <hip/hip_runtime.h>
#include <hip/hip_bf16.h>
#include <cstdint>

#define NV 20000
#define NE 40000
#define NODE_IN 74
#define EDGE_IN 12
#define D 64
#define EHID 128
#define NSTEPS 6

typedef __bf16 bf16x8 __attribute__((ext_vector_type(8)));
typedef float f32x4 __attribute__((ext_vector_type(4)));

// ---------------- node projection: h = relu(nf @ Wp^T + bp); also zero neigh ----------------
__global__ __launch_bounds__(256) void k_proj(const float* __restrict__ nf,
                                              const float* __restrict__ W,
                                              const float* __restrict__ b,
                                              float* __restrict__ h,
                                              float* __restrict__ neigh) {
  __shared__ float sn[4][NODE_IN];
  int tid = threadIdx.x;
  int nb = blockIdx.x * 4;
  for (int idx = tid; idx < 4 * NODE_IN; idx += 256) {
    int r = idx / NODE_IN, c = idx % NODE_IN;
    sn[r][c] = nf[(size_t)(nb + r) * NODE_IN + c];
  }
  __syncthreads();
  int nl = tid >> 6, o = tid & 63;
  float acc = b[o];
#pragma unroll
  for (int i = 0; i < NODE_IN; ++i) acc = fmaf(sn[nl][i], W[o * NODE_IN + i], acc);
  h[(size_t)(nb + nl) * D + o] = fmaxf(acc, 0.f);
  neigh[(size_t)(nb + nl) * D + o] = 0.f;
}

// ------------- edge net layer 1: t = relu(ef @ W1^T + b1), bf16 -------------
__global__ __launch_bounds__(256) void k_edge1(const float* __restrict__ ef,
                                               const float* __restrict__ W1,
                                               const float* __restrict__ b1,
                                               __hip_bfloat16* __restrict__ t_bf) {
  __shared__ float se[2][EDGE_IN];
  int tid = threadIdx.x;
  int eb = blockIdx.x * 2;
  if (tid < 2 * EDGE_IN)
    se[tid / EDGE_IN][tid % EDGE_IN] =
        ef[(size_t)(eb + tid / EDGE_IN) * EDGE_IN + tid % EDGE_IN];
  __syncthreads();
  int el = tid >> 7, k = tid & 127;
  float acc = b1[k];
#pragma unroll
  for (int j = 0; j < EDGE_IN; ++j) acc = fmaf(se[el][j], W1[k * EDGE_IN + j], acc);
  t_bf[(size_t)(eb + el) * EHID + k] = __float2bfloat16(fmaxf(acc, 0.f));
}

// ---------------- W2 fp32 -> bf16 ----------------
__global__ __launch_bounds__(256) void k_cvt_w2(const float* __restrict__ W2,
                                                __hip_bfloat16* __restrict__ w2b) {
  int idx = blockIdx.x * 256 + threadIdx.x;
  if (idx < D * D * EHID) w2b[idx] = __float2bfloat16(W2[idx]);
}

// ------- build GRU B matrix (256 x 128), hi/lo bf16 split -------
__global__ __launch_bounds__(256) void k_build_b(const float* __restrict__ Wih,
                                                 const float* __restrict__ Whh,
                                                 __hip_bfloat16* __restrict__ Bhi,
                                                 __hip_bfloat16* __restrict__ Blo) {
  int idx = blockIdx.x * 256 + threadIdx.x;  // 32768 total
  int n = idx >> 7, k = idx & 127;
  int o = n & 63, cls = n >> 6;
  float v;
  if (cls == 0)      v = (k < 64) ? Wih[o * 64 + k]         : Whh[o * 64 + (k - 64)];
  else if (cls == 1) v = (k < 64) ? Wih[(64 + o) * 64 + k]  : Whh[(64 + o) * 64 + (k - 64)];
  else if (cls == 2) v = (k < 64) ? Wih[(128 + o) * 64 + k] : 0.f;
  else               v = (k < 64) ? 0.f                     : Whh[(128 + o) * 64 + (k - 64)];
  __hip_bfloat16 hi = __float2bfloat16(v);
  Bhi[idx] = hi;
  Blo[idx] = __float2bfloat16(v - __bfloat162float(hi));
}

// ------- fused NNConv message+aggregate: LDS-persistent W2, barrier-free tiles -------
// R11 structure (best: 52.4 µs/step) + R13 inner-loop improvements:
//  * b2 folded into P's accumulator init (fp32, from 2 KB LDS slice; one
//    conflict-free ds_read_b32/ig) — replaces R11's phase-masked b2 MFMAs and
//    their 64 scalar ds_read_u16 per wave-tile.
//  * B-frag reads depth-2 software-pipelined in NAMED reg sets fa/fb (R4 pattern;
//    runtime-indexed arrays spill — R3).
//  * phase-1 h float4s prefetched before phase-0 compute.
__global__ __launch_bounds__(512, 2) void k_msg(const float* __restrict__ h,
                                                const __hip_bfloat16* __restrict__ t_bf,
                                                const __hip_bfloat16* __restrict__ w2,
                                                const float* __restrict__ b2,
                                                const int* __restrict__ src,
                                                const int* __restrict__ dst,
                                                float* __restrict__ neigh) {
  __shared__ __hip_bfloat16 W2s[512 * 128];   // 128 KB, row = ig*16+ol, swizzled k-chunks
  __shared__ __hip_bfloat16 Hs[8][16 * 64];   // 16 KB, per-wave [i_phase][e] bf16
  __shared__ float b2s[32 * 16];              // 2 KB, [ig][ol] fp32
  int tid = threadIdx.x;
  int bx = blockIdx.x;
  int cgc = bx >> 6, ih = (bx >> 5) & 1, st = bx & 31;
  int lane = tid & 63, lr = lane & 15, lq = lane >> 4;
  int wave = tid >> 6;
  const int ocol = cgc * 16 + lr;

  // ---- load W2 slice into LDS (once) ----
#pragma unroll
  for (int it = 0; it < 16; ++it) {
    int chunk = it * 512 + tid;
    int row = chunk >> 4, c = chunk & 15;
    int ig = row >> 4, ol = row & 15;
    const __hip_bfloat16* gp =
        w2 + ((size_t)((ih * 32 + ig) * 64 + cgc * 16 + ol)) * EHID + c * 8;
    *(bf16x8*)(W2s + row * 128 + ((c ^ ol) * 8)) = *(const bf16x8*)gp;
  }
  // b2 slice: b2s[ig*16+ol] = b2[(ih*32+ig)*64 + cgc*16 + ol]
  {
    int ig = tid >> 4, ol = tid & 15;
    b2s[tid] = b2[(ih * 32 + ig) * 64 + cgc * 16 + ol];
  }
  __syncthreads();  // W2s + b2s ready — the ONLY barrier

  __hip_bfloat16* Hsw = &Hs[wave][0];
  int e0s = st * 1280;
  int nt = (st < 31) ? 20 : 5;  // 40000 = 31*1280 + 320

  int sw0 = (((0 * 4 + lq) ^ lr) * 8);
  int sw1 = (((1 * 4 + lq) ^ lr) * 8);
  int sw2 = (((2 * 4 + lq) ^ lr) * 8);
  int sw3 = (((3 * 4 + lq) ^ lr) * 8);

  bf16x8 fa0, fa1, fa2, fa3, fb0, fb1, fb2, fb3;
  float b2a, b2b;

#define LDF(FB, B2V, IG) do {                                            \
    const __hip_bfloat16* Wr_ = W2s + ((IG) * 16 + lr) * 128;            \
    FB##0 = *(const bf16x8*)(Wr_ + sw0);                                 \
    FB##1 = *(const bf16x8*)(Wr_ + sw1);                                 \
    FB##2 = *(const bf16x8*)(Wr_ + sw2);                                 \
    FB##3 = *(const bf16x8*)(Wr_ + sw3);                                 \
    B2V = b2s[(IG) * 16 + lr];                                           \
  } while (0)

#define DO_IG(FB, B2V, IGL) do {                                         \
    _Pragma("unroll")                                                    \
    for (int mt = 0; mt < 4; ++mt) {                                     \
      f32x4 P = {B2V, B2V, B2V, B2V};                                    \
      P = __builtin_amdgcn_mfma_f32_16x16x32_bf16(tf[mt][0], FB##0, P, 0, 0, 0); \
      P = __builtin_amdgcn_mfma_f32_16x16x32_bf16(tf[mt][1], FB##1, P, 0, 0, 0); \
      P = __builtin_amdgcn_mfma_f32_16x16x32_bf16(tf[mt][2], FB##2, P, 0, 0, 0); \
      P = __builtin_amdgcn_mfma_f32_16x16x32_bf16(tf[mt][3], FB##3, P, 0, 0, 0); \
      uint2 hA = *(const uint2*)(Hsw + (IGL) * 64 + mt * 16 + lq * 4);   \
      C[mt][0] = fmaf(__uint_as_float(hA.x << 16), P[0], C[mt][0]);      \
      C[mt][1] = fmaf(__uint_as_float(hA.x & 0xffff0000u), P[1], C[mt][1]); \
      C[mt][2] = fmaf(__uint_as_float(hA.y << 16), P[2], C[mt][2]);      \
      C[mt][3] = fmaf(__uint_as_float(hA.y & 0xffff0000u), P[3], C[mt][3]); \
    }                                                                    \
  } while (0)

#pragma unroll 1
  for (int r3 = 0; r3 < 3; ++r3) {
    int t = r3 * 8 + wave;
    if (t >= nt) break;     // divergence fine: no barriers below
    int e0t = e0s + t * 64;

    bf16x8 tf[4][4];
#pragma unroll
    for (int mt = 0; mt < 4; ++mt)
#pragma unroll
      for (int ks = 0; ks < 4; ++ks)
        tf[mt][ks] = *(const bf16x8*)(t_bf + (size_t)(e0t + mt * 16 + lr) * EHID +
                                      ks * 32 + lq * 8);

    int s_e = src[e0t + lane];
    const float* hrow = h + (size_t)s_e * D + ih * 32;
    // phase-0 h loads
    float4 h00 = *(const float4*)(hrow + 0);
    float4 h01 = *(const float4*)(hrow + 4);
    float4 h02 = *(const float4*)(hrow + 8);
    float4 h03 = *(const float4*)(hrow + 12);

    f32x4 C[4];
#pragma unroll
    for (int mt = 0; mt < 4; ++mt) C[mt] = f32x4{0.f, 0.f, 0.f, 0.f};

    // write phase-0 to Hsw
#define WRHS(Q, HV)                                                      \
    Hsw[((Q)*4 + 0) * 64 + lane] = __float2bfloat16(HV.x);               \
    Hsw[((Q)*4 + 1) * 64 + lane] = __float2bfloat16(HV.y);               \
    Hsw[((Q)*4 + 2) * 64 + lane] = __float2bfloat16(HV.z);               \
    Hsw[((Q)*4 + 3) * 64 + lane] = __float2bfloat16(HV.w);
    WRHS(0, h00) WRHS(1, h01) WRHS(2, h02) WRHS(3, h03)

    // prefetch phase-1 h (drains during phase-0 compute)
    float4 h10 = *(const float4*)(hrow + 16);
    float4 h11 = *(const float4*)(hrow + 20);
    float4 h12 = *(const float4*)(hrow + 24);
    float4 h13 = *(const float4*)(hrow + 28);

    // ---- phase 0: ig 0..15, depth-2 pipelined ----
    LDF(fa, b2a, 0);
#pragma unroll 2
    for (int igl = 0; igl < 16; igl += 2) {
      LDF(fb, b2b, igl + 1);
      DO_IG(fa, b2a, igl);
      if (igl < 14) LDF(fa, b2a, igl + 2);
      DO_IG(fb, b2b, igl + 1);
    }

    // write phase-1 to Hsw (same-wave LDS ops are processed in order)
    WRHS(0, h10) WRHS(1, h11) WRHS(2, h12) WRHS(3, h13)
#undef WRHS

    // ---- phase 1: ig 16..31 ----
    LDF(fa, b2a, 16);
#pragma unroll 2
    for (int igl = 0; igl < 16; igl += 2) {
      LDF(fb, b2b, 16 + igl + 1);
      DO_IG(fa, b2a, igl);
      if (igl < 14) LDF(fa, b2a, 16 + igl + 2);
      DO_IG(fb, b2b, igl + 1);
    }

    // scatter-add (i-halves merge via atomics); overlaps next tile (no barrier)
#pragma unroll
    for (int mt = 0; mt < 4; ++mt) {
#pragma unroll
      for (int r = 0; r < 4; ++r) {
        int ea = e0t + mt * 16 + lq * 4 + r;
        atomicAdd(neigh + (size_t)dst[ea] * D + ocol, C[mt][r]);
      }
    }
  }
#undef LDF
#undef DO_IG
}

// ------- GRU: 32 nodes/block (proven best shape); re-zeroes neigh -------
__global__ __launch_bounds__(256) void k_gru(float* __restrict__ neigh,
                                             float* __restrict__ h,
                                             const __hip_bfloat16* __restrict__ Bhi,
                                             const __hip_bfloat16* __restrict__ Blo,
                                             const float* __restrict__ cb,
                                             const float* __restrict__ bih,
                                             const float* __restrict__ bhh) {
  __shared__ __hip_bfloat16 Ahi[32 * 128];
  __shared__ __hip_bfloat16 Alo[32 * 128];
  int tid = threadIdx.x;
  int n0 = blockIdx.x * 32;  // NV % 32 == 0
  for (int idx = tid; idx < 32 * 64; idx += 256) {
    int node = idx >> 6, f = idx & 63;
    int gn = n0 + node;
    float xv = fmaxf(neigh[(size_t)gn * D + f] + cb[f], 0.f);
    neigh[(size_t)gn * D + f] = 0.f;
    float hv = h[(size_t)gn * D + f];
    __hip_bfloat16 xh = __float2bfloat16(xv);
    __hip_bfloat16 hh = __float2bfloat16(hv);
    Ahi[node * 128 + f] = xh;
    Ahi[node * 128 + 64 + f] = hh;
    Alo[node * 128 + f] = __float2bfloat16(xv - __bfloat162float(xh));
    Alo[node * 128 + 64 + f] = __float2bfloat16(hv - __bfloat162float(hh));
  }
  __syncthreads();
  int wave = tid >> 6, lane = tid & 63;
  int lr = lane & 15, lq = lane >> 4;
  f32x4 acc[2][4] = {};
#pragma unroll
  for (int ks = 0; ks < 4; ++ks) {
    int koff = ks * 32 + lq * 8;
    bf16x8 ah[2], al[2], bh[4], bl[4];
#pragma unroll
    for (int mt = 0; mt < 2; ++mt) {
      ah[mt] = *(const bf16x8*)(Ahi + (mt * 16 + lr) * 128 + koff);
      al[mt] = *(const bf16x8*)(Alo + (mt * 16 + lr) * 128 + koff);
    }
#pragma unroll
    for (int cls = 0; cls < 4; ++cls) {
      int n = cls * 64 + wave * 16 + lr;
      bh[cls] = *(const bf16x8*)(Bhi + (size_t)n * 128 + koff);
      bl[cls] = *(const bf16x8*)(Blo + (size_t)n * 128 + koff);
    }
#pragma unroll
    for (int mt = 0; mt < 2; ++mt)
#pragma unroll
      for (int cls = 0; cls < 4; ++cls) {
        acc[mt][cls] = __builtin_amdgcn_mfma_f32_16x16x32_bf16(ah[mt], bh[cls], acc[mt][cls], 0, 0, 0);
        acc[mt][cls] = __builtin_amdgcn_mfma_f32_16x16x32_bf16(al[mt], bh[cls], acc[mt][cls], 0, 0, 0);
        acc[mt][cls] = __builtin_amdgcn_mfma_f32_16x16x32_bf16(ah[mt], bl[cls], acc[mt][cls], 0, 0, 0);
      }
  }
  int o = wave * 16 + lr;
  float b_r = bih[o] + bhh[o];
  float b_z = bih[64 + o] + bhh[64 + o];
  float b_in = bih[128 + o];
  float b_hn = bhh[128 + o];
#pragma unroll
  for (int mt = 0; mt < 2; ++mt) {
#pragma unroll
    for (int r = 0; r < 4; ++r) {
      int gn = n0 + mt * 16 + lq * 4 + r;
      float rs = acc[mt][0][r] + b_r;
      float zs = acc[mt][1][r] + b_z;
      float inn = acc[mt][2][r] + b_in;
      float hnn = acc[mt][3][r] + b_hn;
      float rg = 1.f / (1.f + __expf(-rs));
      float zg = 1.f / (1.f + __expf(-zs));
      float a = inn + rg * hnn;
      a = fminf(fmaxf(a, -15.f), 15.f);
      float e2 = __expf(2.f * a);
      float nn = (e2 - 1.f) / (e2 + 1.f);
      float hold = h[(size_t)gn * D + o];
      h[(size_t)gn * D + o] = (1.f - zg) * nn + zg * hold;
    }
  }
}

// ---------------- predictor: score_e = [h_src | h_dst] . pW + pb ----------------
__global__ __launch_bounds__(256) void k_pred(const float* __restrict__ h,
                                              const int* __restrict__ src,
                                              const int* __restrict__ dst,
                                              const float* __restrict__ pW,
                                              const float* __restrict__ pb,
                                              float* __restrict__ out) {
  int wave = threadIdx.x >> 6, lane = threadIdx.x & 63;
  int e = blockIdx.x * 4 + wave;
  int s = src[e], d2 = dst[e];
  float v = h[(size_t)s * D + lane] * pW[lane] + h[(size_t)d2 * D + lane] * pW[64 + lane];
#pragma unroll
  for (int off = 32; off >= 1; off >>= 1) v += __shfl_xor(v, off, 64);
  if (lane == 0) out[e] = v + pb[0];
}

extern "C" void kernel_launch(void* const* d_in, const int* in_sizes, int n_in,
                              void* d_out, int out_size, void* d_ws, size_t ws_size,
                              hipStream_t stream) {
  const float* node_feats = (const float*)d_in[0];
  const float* edge_feats = (const float*)d_in[1];
  const int* src = (const int*)d_in[2];
  const int* dst = (const int*)d_in[3];
  const float* proj_W = (const float*)d_in[4];
  const float* proj_b = (const float*)d_in[5];
  const float* en_W1 = (const float*)d_in[6];
  const float* en_b1 = (const float*)d_in[7];
  const float* en_W2 = (const float*)d_in[8];
  const float* en_b2 = (const float*)d_in[9];
  const float* conv_b = (const float*)d_in[10];
  const float* gru_Wih = (const float*)d_in[11];
  const float* gru_Whh = (const float*)d_in[12];
  const float* gru_bih = (const float*)d_in[13];
  const float* gru_bhh = (const float*)d_in[14];
  const float* pred_W = (const float*)d_in[15];
  const float* pred_b = (const float*)d_in[16];

  char* ws = (char*)d_ws;
  size_t off = 0;
  auto walloc = [&](size_t bytes) -> void* {
    void* p = ws + off;
    off = (off + bytes + 255) & ~(size_t)255;
    return p;
  };
  float* h = (float*)walloc((size_t)NV * D * 4);
  float* neigh = (float*)walloc((size_t)NV * D * 4);
  __hip_bfloat16* t_bf = (__hip_bfloat16*)walloc((size_t)NE * EHID * 2);
  __hip_bfloat16* w2_bf = (__hip_bfloat16*)walloc((size_t)D * D * EHID * 2);
  __hip_bfloat16* Bhi = (__hip_bfloat16*)walloc((size_t)256 * 128 * 2);
  __hip_bfloat16* Blo = (__hip_bfloat16*)walloc((size_t)256 * 128 * 2);

  k_proj<<<NV / 4, 256, 0, stream>>>(node_feats, proj_W, proj_b, h, neigh);
  k_edge1<<<NE / 2, 256, 0, stream>>>(edge_feats, en_W1, en_b1, t_bf);
  k_cvt_w2<<<(D * D * EHID + 255) / 256, 256, 0, stream>>>(en_W2, w2_bf);
  k_build_b<<<128, 256, 0, stream>>>(gru_Wih, gru_Whh, Bhi, Blo);
  for (int s = 0; s < NSTEPS; ++s) {
    k_msg<<<256, 512, 0, stream>>>(h, t_bf, w2_bf, en_b2, src, dst, neigh);
    k_gru<<<NV / 32, 256, 0, stream>>>(neigh, h, Bhi, Blo, conv_b, gru_bih, gru_bhh);
  }
  k_pred<<<NE / 4, 256, 0, stream>>>(h, src, dst, pred_W, pred_b, (float*)d_out);
}